// Round 7
// baseline (109.885 us; speedup 1.0000x reference)
//
#include <hip/hip_runtime.h>
#include <hip/hip_bf16.h>

// Shapes (fixed by setup_inputs): B=32, L=2048, V=30522, Dw=300, H=768, S=L/P=128
#define B_   32
#define L_   2048
#define V_   30522
#define DW   300
#define H_   768
#define KP   320              // Dw padded to multiple of 32 for MFMA K
#define NT   (H_/16)          // 48 n-tiles
#define KT   (KP/32)          // 10 k-tiles
#define VPAD 30528            // V rounded up; 30528 = 636 * 48 exactly
#define MB   48               // rows per block (3 m-tiles)
#define NW   12               // n-tiles per wave (4 waves x 12 = 48)

typedef __attribute__((ext_vector_type(8))) short bf16x8;
typedef __attribute__((ext_vector_type(4))) float f32x4;

// ---------------- K0a: pack W [300][768] fp32 -> Wp bf16, fragment f = kt*NT + n --------------
// Wp[f*64 + lane] = 8 bf16: W[k0+j][col], col = n*16 + (lane&15), k0 = kt*32 + (lane>>4)*8.
__global__ void pack_w(const float* __restrict__ W, __hip_bfloat16* __restrict__ Wp) {
    int t = blockIdx.x * 256 + threadIdx.x;           // [0, NT*KT*64)
    if (t >= NT * KT * 64) return;
    int lane = t & 63;
    int f    = t >> 6;
    int n    = f % NT;
    int kt   = f / NT;
    int col  = n * 16 + (lane & 15);
    int k0   = kt * 32 + (lane >> 4) * 8;
    union { __hip_bfloat16 h[8]; int4 v; } u;
    #pragma unroll
    for (int j = 0; j < 8; ++j) {
        int k = k0 + j;
        float w = (k < DW) ? W[(size_t)k * H_ + col] : 0.f;
        u.h[j] = __float2bfloat16(w);
    }
    reinterpret_cast<int4*>(Wp)[t] = u.v;
}

// ---------------- K0b: h1 table [VPAD][KP] bf16 = LN1(emb_table) (one wave per vocab row) -----
__global__ void embed_ln1(const float* __restrict__ emb, const float* __restrict__ g1,
                          const float* __restrict__ b1, __hip_bfloat16* __restrict__ h1) {
    int wave = (blockIdx.x * blockDim.x + threadIdx.x) >> 6;
    int lane = threadIdx.x & 63;
    if (wave >= VPAD) return;
    __hip_bfloat16* dst = h1 + (size_t)wave * KP;
    if (wave >= V_) {                                  // zero pad rows
        for (int k = lane; k < KP; k += 64) dst[k] = __float2bfloat16(0.f);
        return;
    }
    const float* row = emb + (size_t)wave * DW;
    float x[5]; float s = 0.f, ss = 0.f;
    #pragma unroll
    for (int i = 0; i < 5; ++i) {                      // 5*64 = 320 covers KP exactly
        int k = lane + i * 64;
        float v = (k < DW) ? row[k] : 0.f;
        x[i] = v; s += v; ss += v * v;
    }
    #pragma unroll
    for (int m = 32; m >= 1; m >>= 1) { s += __shfl_xor(s, m); ss += __shfl_xor(ss, m); }
    float mu   = s / (float)DW;
    float var  = ss / (float)DW - mu * mu;
    float rstd = rsqrtf(var + 1e-12f);
    #pragma unroll
    for (int i = 0; i < 5; ++i) {
        int k = lane + i * 64;
        float o = (k < DW) ? (g1[k] * ((x[i] - mu) * rstd) + b1[k]) : 0.f;
        dst[k] = __float2bfloat16(o);
    }
}

// ---------------- K1: G[v] = LN2(relu(h1[v] @ W + b)) — N-split, reg-pipelined, barrier-free --
// Block = 48 rows, 4 waves; wave w owns n-tiles [w*12, w*12+12) for ALL 48 rows.
// Half-kt software pipeline: compute 6 fragments x 3 MFMAs from bbuf[s&1] while
// prefetching step s+1's 6 B-fragments into bbuf[(s+1)&1]; A ping-pongs on kt parity.
// Regs: acc 144 + B 48 + A 24 + addr ~15 = ~230 < 256 (no spill at launch_bounds(256,1)).
// C/D layout (m89-verified): col = lane&15, row = (lane>>4)*4 + reg.
__global__ void __launch_bounds__(256, 1)
gemm_ln2(const __hip_bfloat16* __restrict__ h1, const __hip_bfloat16* __restrict__ Wp,
         const float* __restrict__ bias, const float* __restrict__ g2,
         const float* __restrict__ b2, __hip_bfloat16* __restrict__ G) {
    __shared__ float sred[2][4][MB];                   // [s|ss][wave][row] — 1.5 KB
    int w    = threadIdx.x >> 6;
    int lane = threadIdx.x & 63;
    int r = lane & 15, q = lane >> 4;
    size_t row0 = (size_t)blockIdx.x * MB;

    f32x4 acc[NW][3];
    #pragma unroll
    for (int nl = 0; nl < NW; ++nl)
        #pragma unroll
        for (int m = 0; m < 3; ++m) acc[nl][m] = (f32x4){0.f, 0.f, 0.f, 0.f};

    const __hip_bfloat16* a0p = h1 + (row0 + r) * (size_t)KP + q * 8;  // m=0 row fragment
    const bf16x8* Bv = reinterpret_cast<const bf16x8*>(Wp) + (size_t)w * NW * 64 + lane;

    bf16x8 bbuf[2][6];
    bf16x8 abuf[2][3];

    // prologue: step 0's B half-panel and kt=0's A
    #pragma unroll
    for (int i = 0; i < 6; ++i) bbuf[0][i] = Bv[i * 64];
    #pragma unroll
    for (int m = 0; m < 3; ++m)
        abuf[0][m] = *reinterpret_cast<const bf16x8*>(a0p + m * 16 * KP);

    #pragma unroll                                     // FULL unroll: all indices static
    for (int s = 0; s < 2 * KT; ++s) {
        const int kt = s >> 1, hh = s & 1, cb = s & 1, ab = kt & 1;
        if (s + 1 < 2 * KT) {                          // prefetch next half-panel of B
            const int kt2 = (s + 1) >> 1, hh2 = (s + 1) & 1;
            const bf16x8* bp = Bv + ((size_t)kt2 * NT + hh2 * 6) * 64;
            #pragma unroll
            for (int i = 0; i < 6; ++i) bbuf[(s + 1) & 1][i] = bp[i * 64];
        }
        if (hh == 0 && kt + 1 < KT) {                  // prefetch next kt's A
            #pragma unroll
            for (int m = 0; m < 3; ++m)
                abuf[(kt + 1) & 1][m] =
                    *reinterpret_cast<const bf16x8*>(a0p + m * 16 * KP + (kt + 1) * 32);
        }
        #pragma unroll
        for (int i = 0; i < 6; ++i) {                  // 6 fragments x 3 MFMAs
            const int nl = hh * 6 + i;
            bf16x8 bv = bbuf[cb][i];
            acc[nl][0] = __builtin_amdgcn_mfma_f32_16x16x32_bf16(abuf[ab][0], bv, acc[nl][0], 0, 0, 0);
            acc[nl][1] = __builtin_amdgcn_mfma_f32_16x16x32_bf16(abuf[ab][1], bv, acc[nl][1], 0, 0, 0);
            acc[nl][2] = __builtin_amdgcn_mfma_f32_16x16x32_bf16(abuf[ab][2], bv, acc[nl][2], 0, 0, 0);
        }
    }

    // bias + relu + in-wave partial stats (over this wave's 192 cols)
    float s_[3][4], ss_[3][4];
    #pragma unroll
    for (int m = 0; m < 3; ++m)
        #pragma unroll
        for (int j = 0; j < 4; ++j) { s_[m][j] = 0.f; ss_[m][j] = 0.f; }
    #pragma unroll
    for (int nl = 0; nl < NW; ++nl) {
        float bn = bias[w * 192 + nl * 16 + r];
        #pragma unroll
        for (int m = 0; m < 3; ++m)
            #pragma unroll
            for (int j = 0; j < 4; ++j) {
                float v = acc[nl][m][j] + bn;
                v = v > 0.f ? v : 0.f;
                acc[nl][m][j] = v;
                s_[m][j] += v; ss_[m][j] += v * v;
            }
    }
    #pragma unroll
    for (int msk = 1; msk < 16; msk <<= 1)             // reduce across the 16 r-lanes
        #pragma unroll
        for (int m = 0; m < 3; ++m)
            #pragma unroll
            for (int j = 0; j < 4; ++j) {
                s_[m][j]  += __shfl_xor(s_[m][j],  msk);
                ss_[m][j] += __shfl_xor(ss_[m][j], msk);
            }
    if (r == 0) {                                      // publish wave partials
        #pragma unroll
        for (int m = 0; m < 3; ++m)
            #pragma unroll
            for (int j = 0; j < 4; ++j) {
                int row = m * 16 + q * 4 + j;
                sred[0][w][row] = s_[m][j];
                sred[1][w][row] = ss_[m][j];
            }
    }
    __syncthreads();

    #pragma unroll
    for (int m = 0; m < 3; ++m) {
        #pragma unroll
        for (int j = 0; j < 4; ++j) {
            int row = m * 16 + q * 4 + j;
            float ts  = sred[0][0][row] + sred[0][1][row] + sred[0][2][row] + sred[0][3][row];
            float tss = sred[1][0][row] + sred[1][1][row] + sred[1][2][row] + sred[1][3][row];
            float mu   = ts / (float)H_;
            float var  = tss / (float)H_ - mu * mu;
            float rstd = rsqrtf(var + 1e-12f);
            s_[m][j]  = mu;                            // reuse as mu
            ss_[m][j] = rstd;                          // reuse as rstd
        }
    }
    #pragma unroll
    for (int nl = 0; nl < NW; ++nl) {
        int col = w * 192 + nl * 16 + r;
        float gg = g2[col], bb = b2[col];
        #pragma unroll
        for (int m = 0; m < 3; ++m)
            #pragma unroll
            for (int j = 0; j < 4; ++j) {
                size_t rowg = row0 + m * 16 + q * 4 + j;
                float val = gg * (acc[nl][m][j] - s_[m][j]) * ss_[m][j] + bb;
                G[rowg * H_ + col] = __float2bfloat16(val);
            }
    }
}

// ---------------- K1.5: per-batch-row separator positions (general mask handling) -------------
__global__ void sep_scan(const int* __restrict__ sep, int* __restrict__ pos, int* __restrict__ nsep) {
    int b = blockIdx.x;
    const int* row = sep + (size_t)b * L_;
    __shared__ int cnt[256];
    int tid = threadIdx.x;
    int local[8]; int c = 0;
    #pragma unroll
    for (int i = 0; i < 8; ++i) { int v = row[tid * 8 + i]; local[i] = v; c += v; }
    cnt[tid] = c; __syncthreads();
    for (int ofs = 1; ofs < 256; ofs <<= 1) {          // Hillis-Steele inclusive scan
        int v = (tid >= ofs) ? cnt[tid - ofs] : 0;
        __syncthreads();
        cnt[tid] += v;
        __syncthreads();
    }
    int w = cnt[tid] - c;                              // exclusive prefix
    #pragma unroll
    for (int i = 0; i < 8; ++i)
        if (local[i]) { pos[(size_t)b * L_ + w] = tid * 8 + i; ++w; }
    if (tid == 255) nsep[b] = cnt[255];
}

// ---------------- K2: out[b,s,:] = mean_{t in seg(b,s)} G[ids[b,t]] + PE[s] -------------------
__global__ void seg_gather(const int* __restrict__ ids, const int* __restrict__ pos,
                           const int* __restrict__ nsep, const __hip_bfloat16* __restrict__ G,
                           float* __restrict__ out, int S) {
    int blk = blockIdx.x;
    int s = blk % S, b = blk / S;
    int tid = threadIdx.x;                             // 256 threads, 3 cols each
    int ns = nsep[b];
    int lo, hi;
    if (s > ns) { lo = 1; hi = 0; }                    // empty segment
    else {
        lo = (s == 0) ? 0 : pos[(size_t)b * L_ + (s - 1)] + 1;
        hi = (s < ns) ? pos[(size_t)b * L_ + s] - 1 : L_ - 1;   // s==ns: tail after last sep
    }
    int cnt = hi - lo + 1; if (cnt < 0) cnt = 0;
    float a0 = 0.f, a1 = 0.f, a2 = 0.f;
    for (int t = lo; t <= hi; ++t) {
        int v = ids[(size_t)b * L_ + t];
        const __hip_bfloat16* gr = G + (size_t)v * H_;
        a0 += __bfloat162float(gr[tid]);
        a1 += __bfloat162float(gr[tid + 256]);
        a2 += __bfloat162float(gr[tid + 512]);
    }
    float inv = (cnt > 0) ? 1.f / (float)cnt : 0.f;
    float* orow = out + ((size_t)b * S + s) * H_;
    const float cexp = -9.210340371976184f / (float)H_;   // -ln(10000)/H
    float acc[3] = {a0, a1, a2};
    #pragma unroll
    for (int c = 0; c < 3; ++c) {
        int n = tid + c * 256;
        int i = n >> 1;
        float div = expf((float)(2 * i) * cexp);
        float ang = (float)s * div;
        float pe  = (n & 1) ? cosf(ang) : sinf(ang);
        orow[n] = acc[c] * inv + pe;
    }
}

// ---------------- host launcher ----------------
extern "C" void kernel_launch(void* const* d_in, const int* in_sizes, int n_in,
                              void* d_out, int out_size, void* d_ws, size_t ws_size,
                              hipStream_t stream) {
    const int*   ids  = (const int*)d_in[0];
    const int*   sep  = (const int*)d_in[1];
    const float* emb  = (const float*)d_in[3];
    const float* g1   = (const float*)d_in[4];
    const float* b1   = (const float*)d_in[5];
    const float* W    = (const float*)d_in[6];
    const float* bias = (const float*)d_in[7];
    const float* g2   = (const float*)d_in[8];
    const float* b2   = (const float*)d_in[9];
    float* out = (float*)d_out;

    int S = out_size / (B_ * H_);                      // 128

    // workspace layout (all 256B-aligned)
    char* ws = (char*)d_ws;
    __hip_bfloat16* Wp  = (__hip_bfloat16*)(ws);                         // 491,520 B
    __hip_bfloat16* h1  = (__hip_bfloat16*)(ws + 491520);                // 19,537,920 B
    __hip_bfloat16* G   = (__hip_bfloat16*)(ws + 491520 + 19537920);     // 46,891,008 B
    int* pos  = (int*)(ws + 491520 + 19537920 + 46891008);               // 262,144 B
    int* nsep = (int*)(ws + 491520 + 19537920 + 46891008 + 262144);      // 128 B
    (void)ws_size; (void)n_in; (void)in_sizes;

    pack_w   <<<(NT * KT * 64 + 255) / 256, 256, 0, stream>>>(W, Wp);
    embed_ln1<<<VPAD / 4, 256, 0, stream>>>(emb, g1, b1, h1);
    gemm_ln2 <<<VPAD / MB, 256, 0, stream>>>(h1, Wp, bias, g2, b2, G);
    sep_scan <<<B_, 256, 0, stream>>>(sep, pos, nsep);
    seg_gather<<<B_ * S, 256, 0, stream>>>(ids, pos, nsep, G, out, S);
}

// Round 8
// 98.141 us; speedup vs baseline: 1.1197x; 1.1197x over previous
//
#include <hip/hip_runtime.h>
#include <hip/hip_bf16.h>

// Shapes (fixed by setup_inputs): B=32, L=2048, V=30522, Dw=300, H=768, S=L/P=128
#define B_   32
#define L_   2048
#define V_   30522
#define DW   300
#define H_   768
#define KP   320              // Dw padded to multiple of 32 for MFMA K
#define NT   (H_/16)          // 48 n-tiles
#define KT   (KP/32)          // 10 k-tiles
#define VPAD 30528            // V rounded up; 30528 = 636 * 48 exactly
#define MB   48               // rows per block (3 m-tiles)
#define NW   6                // n-tiles per wave (8 waves x 6 = 48)

typedef __attribute__((ext_vector_type(8))) short bf16x8;
typedef __attribute__((ext_vector_type(4))) float f32x4;

// ---------------- K0a: pack W [300][768] fp32 -> Wp bf16, fragment f = kt*NT + n --------------
// Wp[f*64 + lane] = 8 bf16: W[k0+j][col], col = n*16 + (lane&15), k0 = kt*32 + (lane>>4)*8.
__global__ void pack_w(const float* __restrict__ W, __hip_bfloat16* __restrict__ Wp) {
    int t = blockIdx.x * 256 + threadIdx.x;           // [0, NT*KT*64)
    if (t >= NT * KT * 64) return;
    int lane = t & 63;
    int f    = t >> 6;
    int n    = f % NT;
    int kt   = f / NT;
    int col  = n * 16 + (lane & 15);
    int k0   = kt * 32 + (lane >> 4) * 8;
    union { __hip_bfloat16 h[8]; int4 v; } u;
    #pragma unroll
    for (int j = 0; j < 8; ++j) {
        int k = k0 + j;
        float w = (k < DW) ? W[(size_t)k * H_ + col] : 0.f;
        u.h[j] = __float2bfloat16(w);
    }
    reinterpret_cast<int4*>(Wp)[t] = u.v;
}

// ---------------- K0b: h1 table [VPAD][KP] bf16 = LN1(emb_table) (one wave per vocab row) -----
__global__ void embed_ln1(const float* __restrict__ emb, const float* __restrict__ g1,
                          const float* __restrict__ b1, __hip_bfloat16* __restrict__ h1) {
    int wave = (blockIdx.x * blockDim.x + threadIdx.x) >> 6;
    int lane = threadIdx.x & 63;
    if (wave >= VPAD) return;
    __hip_bfloat16* dst = h1 + (size_t)wave * KP;
    if (wave >= V_) {                                  // zero pad rows
        for (int k = lane; k < KP; k += 64) dst[k] = __float2bfloat16(0.f);
        return;
    }
    const float* row = emb + (size_t)wave * DW;
    float x[5]; float s = 0.f, ss = 0.f;
    #pragma unroll
    for (int i = 0; i < 5; ++i) {                      // 5*64 = 320 covers KP exactly
        int k = lane + i * 64;
        float v = (k < DW) ? row[k] : 0.f;
        x[i] = v; s += v; ss += v * v;
    }
    #pragma unroll
    for (int m = 32; m >= 1; m >>= 1) { s += __shfl_xor(s, m); ss += __shfl_xor(ss, m); }
    float mu   = s / (float)DW;
    float var  = ss / (float)DW - mu * mu;
    float rstd = rsqrtf(var + 1e-12f);
    #pragma unroll
    for (int i = 0; i < 5; ++i) {
        int k = lane + i * 64;
        float o = (k < DW) ? (g1[k] * ((x[i] - mu) * rstd) + b1[k]) : 0.f;
        dst[k] = __float2bfloat16(o);
    }
}

// ---------------- K1: G[v] = LN2(relu(h1[v] @ W + b)) — 8-wave N-split, barrier-free K loop ---
// Block = 48 rows, 8 waves (512 thr); wave w owns n-tiles [w*6, w*6+6) for ALL 48 rows.
// acc = 6x3 f32x4 = 72 VGPR (halved vs r6) -> ~100 free regs for in-flight loads; the
// compiler pipelines loads across kt (r7 showed manual ping-pong hurts — let it schedule).
// B straight from L2 (Wp 480 KB resident, 1KB contiguous per load, reused 3x in regs).
// C/D layout (m89-verified): col = lane&15, row = (lane>>4)*4 + reg.
__global__ void __launch_bounds__(512, 1)
gemm_ln2(const __hip_bfloat16* __restrict__ h1, const __hip_bfloat16* __restrict__ Wp,
         const float* __restrict__ bias, const float* __restrict__ g2,
         const float* __restrict__ b2, __hip_bfloat16* __restrict__ G) {
    __shared__ float sred[2][8][MB];                   // [s|ss][wave][row] — 3 KB
    int w    = threadIdx.x >> 6;
    int lane = threadIdx.x & 63;
    int r = lane & 15, q = lane >> 4;
    size_t row0 = (size_t)blockIdx.x * MB;

    f32x4 acc[NW][3];
    #pragma unroll
    for (int nl = 0; nl < NW; ++nl)
        #pragma unroll
        for (int m = 0; m < 3; ++m) acc[nl][m] = (f32x4){0.f, 0.f, 0.f, 0.f};

    const __hip_bfloat16* a0p = h1 + (row0 + r) * (size_t)KP + q * 8;  // m=0 row fragment
    const bf16x8* Bv = reinterpret_cast<const bf16x8*>(Wp) + (size_t)w * NW * 64 + lane;

    #pragma unroll 2
    for (int kt = 0; kt < KT; ++kt) {
        const bf16x8* bp = Bv + (size_t)kt * NT * 64;
        bf16x8 bv[NW];
        #pragma unroll
        for (int nl = 0; nl < NW; ++nl) bv[nl] = bp[nl * 64];   // 6 x 1KB contiguous
        bf16x8 a0 = *reinterpret_cast<const bf16x8*>(a0p + kt * 32);
        bf16x8 a1 = *reinterpret_cast<const bf16x8*>(a0p + 16 * KP + kt * 32);
        bf16x8 a2 = *reinterpret_cast<const bf16x8*>(a0p + 32 * KP + kt * 32);
        #pragma unroll                                 // static acc indices (rule #20)
        for (int nl = 0; nl < NW; ++nl) {
            acc[nl][0] = __builtin_amdgcn_mfma_f32_16x16x32_bf16(a0, bv[nl], acc[nl][0], 0, 0, 0);
            acc[nl][1] = __builtin_amdgcn_mfma_f32_16x16x32_bf16(a1, bv[nl], acc[nl][1], 0, 0, 0);
            acc[nl][2] = __builtin_amdgcn_mfma_f32_16x16x32_bf16(a2, bv[nl], acc[nl][2], 0, 0, 0);
        }
    }

    // bias + relu + in-wave partial stats (over this wave's 96 cols)
    float s_[3][4], ss_[3][4];
    #pragma unroll
    for (int m = 0; m < 3; ++m)
        #pragma unroll
        for (int j = 0; j < 4; ++j) { s_[m][j] = 0.f; ss_[m][j] = 0.f; }
    #pragma unroll
    for (int nl = 0; nl < NW; ++nl) {
        float bn = bias[w * 96 + nl * 16 + r];
        #pragma unroll
        for (int m = 0; m < 3; ++m)
            #pragma unroll
            for (int j = 0; j < 4; ++j) {
                float v = acc[nl][m][j] + bn;
                v = v > 0.f ? v : 0.f;
                acc[nl][m][j] = v;
                s_[m][j] += v; ss_[m][j] += v * v;
            }
    }
    #pragma unroll
    for (int msk = 1; msk < 16; msk <<= 1)             // reduce across the 16 r-lanes
        #pragma unroll
        for (int m = 0; m < 3; ++m)
            #pragma unroll
            for (int j = 0; j < 4; ++j) {
                s_[m][j]  += __shfl_xor(s_[m][j],  msk);
                ss_[m][j] += __shfl_xor(ss_[m][j], msk);
            }
    if (r == 0) {                                      // publish wave partials
        #pragma unroll
        for (int m = 0; m < 3; ++m)
            #pragma unroll
            for (int j = 0; j < 4; ++j) {
                int row = m * 16 + q * 4 + j;
                sred[0][w][row] = s_[m][j];
                sred[1][w][row] = ss_[m][j];
            }
    }
    __syncthreads();

    #pragma unroll
    for (int m = 0; m < 3; ++m) {
        #pragma unroll
        for (int j = 0; j < 4; ++j) {
            int row = m * 16 + q * 4 + j;
            float ts = 0.f, tss = 0.f;
            #pragma unroll
            for (int ww = 0; ww < 8; ++ww) { ts += sred[0][ww][row]; tss += sred[1][ww][row]; }
            float mu   = ts / (float)H_;
            float var  = tss / (float)H_ - mu * mu;
            float rstd = rsqrtf(var + 1e-12f);
            s_[m][j]  = mu;                            // reuse as mu
            ss_[m][j] = rstd;                          // reuse as rstd
        }
    }
    #pragma unroll
    for (int nl = 0; nl < NW; ++nl) {
        int col = w * 96 + nl * 16 + r;
        float gg = g2[col], bb = b2[col];
        #pragma unroll
        for (int m = 0; m < 3; ++m)
            #pragma unroll
            for (int j = 0; j < 4; ++j) {
                size_t rowg = row0 + m * 16 + q * 4 + j;
                float val = gg * (acc[nl][m][j] - s_[m][j]) * ss_[m][j] + bb;
                G[rowg * H_ + col] = __float2bfloat16(val);
            }
    }
}

// ---------------- K1.5: per-batch-row separator positions (general mask handling) -------------
__global__ void sep_scan(const int* __restrict__ sep, int* __restrict__ pos, int* __restrict__ nsep) {
    int b = blockIdx.x;
    const int* row = sep + (size_t)b * L_;
    __shared__ int cnt[256];
    int tid = threadIdx.x;
    int local[8]; int c = 0;
    #pragma unroll
    for (int i = 0; i < 8; ++i) { int v = row[tid * 8 + i]; local[i] = v; c += v; }
    cnt[tid] = c; __syncthreads();
    for (int ofs = 1; ofs < 256; ofs <<= 1) {          // Hillis-Steele inclusive scan
        int v = (tid >= ofs) ? cnt[tid - ofs] : 0;
        __syncthreads();
        cnt[tid] += v;
        __syncthreads();
    }
    int w = cnt[tid] - c;                              // exclusive prefix
    #pragma unroll
    for (int i = 0; i < 8; ++i)
        if (local[i]) { pos[(size_t)b * L_ + w] = tid * 8 + i; ++w; }
    if (tid == 255) nsep[b] = cnt[255];
}

// ---------------- K2: out[b,s,:] = mean_{t in seg(b,s)} G[ids[b,t]] + PE[s] -------------------
__global__ void seg_gather(const int* __restrict__ ids, const int* __restrict__ pos,
                           const int* __restrict__ nsep, const __hip_bfloat16* __restrict__ G,
                           float* __restrict__ out, int S) {
    int blk = blockIdx.x;
    int s = blk % S, b = blk / S;
    int tid = threadIdx.x;                             // 256 threads, 3 cols each
    int ns = nsep[b];
    int lo, hi;
    if (s > ns) { lo = 1; hi = 0; }                    // empty segment
    else {
        lo = (s == 0) ? 0 : pos[(size_t)b * L_ + (s - 1)] + 1;
        hi = (s < ns) ? pos[(size_t)b * L_ + s] - 1 : L_ - 1;   // s==ns: tail after last sep
    }
    int cnt = hi - lo + 1; if (cnt < 0) cnt = 0;
    float a0 = 0.f, a1 = 0.f, a2 = 0.f;
    for (int t = lo; t <= hi; ++t) {
        int v = ids[(size_t)b * L_ + t];
        const __hip_bfloat16* gr = G + (size_t)v * H_;
        a0 += __bfloat162float(gr[tid]);
        a1 += __bfloat162float(gr[tid + 256]);
        a2 += __bfloat162float(gr[tid + 512]);
    }
    float inv = (cnt > 0) ? 1.f / (float)cnt : 0.f;
    float* orow = out + ((size_t)b * S + s) * H_;
    const float cexp = -9.210340371976184f / (float)H_;   // -ln(10000)/H
    float acc[3] = {a0, a1, a2};
    #pragma unroll
    for (int c = 0; c < 3; ++c) {
        int n = tid + c * 256;
        int i = n >> 1;
        float div = expf((float)(2 * i) * cexp);
        float ang = (float)s * div;
        float pe  = (n & 1) ? cosf(ang) : sinf(ang);
        orow[n] = acc[c] * inv + pe;
    }
}

// ---------------- host launcher ----------------
extern "C" void kernel_launch(void* const* d_in, const int* in_sizes, int n_in,
                              void* d_out, int out_size, void* d_ws, size_t ws_size,
                              hipStream_t stream) {
    const int*   ids  = (const int*)d_in[0];
    const int*   sep  = (const int*)d_in[1];
    const float* emb  = (const float*)d_in[3];
    const float* g1   = (const float*)d_in[4];
    const float* b1   = (const float*)d_in[5];
    const float* W    = (const float*)d_in[6];
    const float* bias = (const float*)d_in[7];
    const float* g2   = (const float*)d_in[8];
    const float* b2   = (const float*)d_in[9];
    float* out = (float*)d_out;

    int S = out_size / (B_ * H_);                      // 128

    // workspace layout (all 256B-aligned)
    char* ws = (char*)d_ws;
    __hip_bfloat16* Wp  = (__hip_bfloat16*)(ws);                         // 491,520 B
    __hip_bfloat16* h1  = (__hip_bfloat16*)(ws + 491520);                // 19,537,920 B
    __hip_bfloat16* G   = (__hip_bfloat16*)(ws + 491520 + 19537920);     // 46,891,008 B
    int* pos  = (int*)(ws + 491520 + 19537920 + 46891008);               // 262,144 B
    int* nsep = (int*)(ws + 491520 + 19537920 + 46891008 + 262144);      // 128 B
    (void)ws_size; (void)n_in; (void)in_sizes;

    pack_w   <<<(NT * KT * 64 + 255) / 256, 256, 0, stream>>>(W, Wp);
    embed_ln1<<<VPAD / 4, 256, 0, stream>>>(emb, g1, b1, h1);
    gemm_ln2 <<<VPAD / MB, 512, 0, stream>>>(h1, Wp, bias, g2, b2, G);
    sep_scan <<<B_, 256, 0, stream>>>(sep, pos, nsep);
    seg_gather<<<B_ * S, 256, 0, stream>>>(ids, pos, nsep, G, out, S);
}

// Round 9
// 86.287 us; speedup vs baseline: 1.2735x; 1.1374x over previous
//
#include <hip/hip_runtime.h>
#include <hip/hip_bf16.h>

// Shapes (fixed by setup_inputs): B=32, L=2048, V=30522, Dw=300, H=768, S=L/P=128
#define B_   32
#define L_   2048
#define V_   30522
#define DW   300
#define H_   768
#define KP   320              // Dw padded to multiple of 32 for MFMA K
#define NT   (H_/16)          // 48 n-tiles
#define KT   (KP/32)          // 10 k-tiles
#define VPAD 30528            // V rounded up; 30528 = 636 * 48 exactly
#define MB   48               // rows per block (3 m-tiles)
#define NW   6                // n-tiles per wave (8 waves x 6 = 48)
#define APAD 328              // padded LDS row stride (bf16): dword stride 164 -> b128 reads
                              // land at 4*(r+q) mod 32 -> exactly-minimum bank usage

typedef __attribute__((ext_vector_type(8))) short bf16x8;
typedef __attribute__((ext_vector_type(4))) float f32x4;

// ---------------- K0a: pack W [300][768] fp32 -> Wp bf16, fragment f = kt*NT + n --------------
// Wp[f*64 + lane] = 8 bf16: W[k0+j][col], col = n*16 + (lane&15), k0 = kt*32 + (lane>>4)*8.
__global__ void pack_w(const float* __restrict__ W, __hip_bfloat16* __restrict__ Wp) {
    int t = blockIdx.x * 256 + threadIdx.x;           // [0, NT*KT*64)
    if (t >= NT * KT * 64) return;
    int lane = t & 63;
    int f    = t >> 6;
    int n    = f % NT;
    int kt   = f / NT;
    int col  = n * 16 + (lane & 15);
    int k0   = kt * 32 + (lane >> 4) * 8;
    union { __hip_bfloat16 h[8]; int4 v; } u;
    #pragma unroll
    for (int j = 0; j < 8; ++j) {
        int k = k0 + j;
        float w = (k < DW) ? W[(size_t)k * H_ + col] : 0.f;
        u.h[j] = __float2bfloat16(w);
    }
    reinterpret_cast<int4*>(Wp)[t] = u.v;
}

// ---------------- K0b: h1 table [VPAD][KP] bf16 = LN1(emb_table) (one wave per vocab row) -----
__global__ void embed_ln1(const float* __restrict__ emb, const float* __restrict__ g1,
                          const float* __restrict__ b1, __hip_bfloat16* __restrict__ h1) {
    int wave = (blockIdx.x * blockDim.x + threadIdx.x) >> 6;
    int lane = threadIdx.x & 63;
    if (wave >= VPAD) return;
    __hip_bfloat16* dst = h1 + (size_t)wave * KP;
    if (wave >= V_) {                                  // zero pad rows
        for (int k = lane; k < KP; k += 64) dst[k] = __float2bfloat16(0.f);
        return;
    }
    const float* row = emb + (size_t)wave * DW;
    float x[5]; float s = 0.f, ss = 0.f;
    #pragma unroll
    for (int i = 0; i < 5; ++i) {                      // 5*64 = 320 covers KP exactly
        int k = lane + i * 64;
        float v = (k < DW) ? row[k] : 0.f;
        x[i] = v; s += v; ss += v * v;
    }
    #pragma unroll
    for (int m = 32; m >= 1; m >>= 1) { s += __shfl_xor(s, m); ss += __shfl_xor(ss, m); }
    float mu   = s / (float)DW;
    float var  = ss / (float)DW - mu * mu;
    float rstd = rsqrtf(var + 1e-12f);
    #pragma unroll
    for (int i = 0; i < 5; ++i) {
        int k = lane + i * 64;
        float o = (k < DW) ? (g1[k] * ((x[i] - mu) * rstd) + b1[k]) : 0.f;
        dst[k] = __float2bfloat16(o);
    }
}

// ---------------- K1: G[v] = LN2(relu(h1[v] @ W + b)) — A-in-LDS, kt-rotated, 8-wave ----------
// Block = 48 rows, 8 waves (512 thr); wave w owns n-tiles [w*6, w*6+6) for ALL 48 rows.
// (a) A staged ONCE to LDS (31 KB, padded) -> no HBM latency inside K loop;
// (b) kt loop rotated by blockIdx%KT -> blocks walk Wp out of phase (L2 de-hotspot);
// (c) LDS 34.5 KB + low VGPR -> up to 4 blocks/CU (32 waves) for TLP.
// C/D layout (m89-verified): col = lane&15, row = (lane>>4)*4 + reg.
__global__ void __launch_bounds__(512, 1)
gemm_ln2(const __hip_bfloat16* __restrict__ h1, const __hip_bfloat16* __restrict__ Wp,
         const float* __restrict__ bias, const float* __restrict__ g2,
         const float* __restrict__ b2, __hip_bfloat16* __restrict__ G) {
    __shared__ __hip_bfloat16 sA[MB * APAD];           // 31,488 B
    __shared__ float sred[2][8][MB];                   // 3 KB
    int tid  = threadIdx.x;
    int w    = tid >> 6;
    int lane = tid & 63;
    int r = lane & 15, q = lane >> 4;
    size_t row0 = (size_t)blockIdx.x * MB;

    // ---- stage A: 48 rows x 320 bf16 (30,720 B contiguous in h1) -> padded LDS ----
    const int4* gsrc = reinterpret_cast<const int4*>(h1 + row0 * KP);
    #pragma unroll
    for (int i = 0; i < 4; ++i) {
        int t4 = tid + i * 512;                        // int4 index, [0, 1920)
        if (t4 < MB * KP / 8) {
            int e0  = t4 * 8;
            int row = e0 / KP, col = e0 % KP;          // col multiple of 8 -> 16B aligned
            *reinterpret_cast<int4*>(&sA[row * APAD + col]) = gsrc[t4];
        }
    }
    __syncthreads();

    f32x4 acc[NW][3];
    #pragma unroll
    for (int nl = 0; nl < NW; ++nl)
        #pragma unroll
        for (int m = 0; m < 3; ++m) acc[nl][m] = (f32x4){0.f, 0.f, 0.f, 0.f};

    const __hip_bfloat16* aL = sA + r * APAD + q * 8;  // lane's A base (m=0)
    const bf16x8* Bv = reinterpret_cast<const bf16x8*>(Wp) + (size_t)w * NW * 64 + lane;
    int phase = (int)(blockIdx.x % KT);

    #pragma unroll 2
    for (int i = 0; i < KT; ++i) {
        int kt = i + phase; if (kt >= KT) kt -= KT;    // rotated walk over Wp
        const bf16x8* bp = Bv + (size_t)kt * NT * 64;
        bf16x8 bv[NW];
        #pragma unroll
        for (int nl = 0; nl < NW; ++nl) bv[nl] = bp[nl * 64];   // 6 x 1KB contiguous (L2)
        bf16x8 a0 = *reinterpret_cast<const bf16x8*>(aL + kt * 32);
        bf16x8 a1 = *reinterpret_cast<const bf16x8*>(aL + 16 * APAD + kt * 32);
        bf16x8 a2 = *reinterpret_cast<const bf16x8*>(aL + 32 * APAD + kt * 32);
        #pragma unroll                                 // static acc indices (rule #20)
        for (int nl = 0; nl < NW; ++nl) {
            acc[nl][0] = __builtin_amdgcn_mfma_f32_16x16x32_bf16(a0, bv[nl], acc[nl][0], 0, 0, 0);
            acc[nl][1] = __builtin_amdgcn_mfma_f32_16x16x32_bf16(a1, bv[nl], acc[nl][1], 0, 0, 0);
            acc[nl][2] = __builtin_amdgcn_mfma_f32_16x16x32_bf16(a2, bv[nl], acc[nl][2], 0, 0, 0);
        }
    }

    // bias + relu + in-wave partial stats (over this wave's 96 cols)
    float s_[3][4], ss_[3][4];
    #pragma unroll
    for (int m = 0; m < 3; ++m)
        #pragma unroll
        for (int j = 0; j < 4; ++j) { s_[m][j] = 0.f; ss_[m][j] = 0.f; }
    #pragma unroll
    for (int nl = 0; nl < NW; ++nl) {
        float bn = bias[w * 96 + nl * 16 + r];
        #pragma unroll
        for (int m = 0; m < 3; ++m)
            #pragma unroll
            for (int j = 0; j < 4; ++j) {
                float v = acc[nl][m][j] + bn;
                v = v > 0.f ? v : 0.f;
                acc[nl][m][j] = v;
                s_[m][j] += v; ss_[m][j] += v * v;
            }
    }
    #pragma unroll
    for (int msk = 1; msk < 16; msk <<= 1)             // reduce across the 16 r-lanes
        #pragma unroll
        for (int m = 0; m < 3; ++m)
            #pragma unroll
            for (int j = 0; j < 4; ++j) {
                s_[m][j]  += __shfl_xor(s_[m][j],  msk);
                ss_[m][j] += __shfl_xor(ss_[m][j], msk);
            }
    if (r == 0) {                                      // publish wave partials
        #pragma unroll
        for (int m = 0; m < 3; ++m)
            #pragma unroll
            for (int j = 0; j < 4; ++j) {
                int row = m * 16 + q * 4 + j;
                sred[0][w][row] = s_[m][j];
                sred[1][w][row] = ss_[m][j];
            }
    }
    __syncthreads();

    #pragma unroll
    for (int m = 0; m < 3; ++m) {
        #pragma unroll
        for (int j = 0; j < 4; ++j) {
            int row = m * 16 + q * 4 + j;
            float ts = 0.f, tss = 0.f;
            #pragma unroll
            for (int ww = 0; ww < 8; ++ww) { ts += sred[0][ww][row]; tss += sred[1][ww][row]; }
            float mu   = ts / (float)H_;
            float var  = tss / (float)H_ - mu * mu;
            float rstd = rsqrtf(var + 1e-12f);
            s_[m][j]  = mu;                            // reuse as mu
            ss_[m][j] = rstd;                          // reuse as rstd
        }
    }
    #pragma unroll
    for (int nl = 0; nl < NW; ++nl) {
        int col = w * 96 + nl * 16 + r;
        float gg = g2[col], bb = b2[col];
        #pragma unroll
        for (int m = 0; m < 3; ++m)
            #pragma unroll
            for (int j = 0; j < 4; ++j) {
                size_t rowg = row0 + m * 16 + q * 4 + j;
                float val = gg * (acc[nl][m][j] - s_[m][j]) * ss_[m][j] + bb;
                G[rowg * H_ + col] = __float2bfloat16(val);
            }
    }
}

// ---------------- K1.5: per-batch-row separator positions (general mask handling) -------------
__global__ void sep_scan(const int* __restrict__ sep, int* __restrict__ pos, int* __restrict__ nsep) {
    int b = blockIdx.x;
    const int* row = sep + (size_t)b * L_;
    __shared__ int cnt[256];
    int tid = threadIdx.x;
    int local[8]; int c = 0;
    #pragma unroll
    for (int i = 0; i < 8; ++i) { int v = row[tid * 8 + i]; local[i] = v; c += v; }
    cnt[tid] = c; __syncthreads();
    for (int ofs = 1; ofs < 256; ofs <<= 1) {          // Hillis-Steele inclusive scan
        int v = (tid >= ofs) ? cnt[tid - ofs] : 0;
        __syncthreads();
        cnt[tid] += v;
        __syncthreads();
    }
    int w = cnt[tid] - c;                              // exclusive prefix
    #pragma unroll
    for (int i = 0; i < 8; ++i)
        if (local[i]) { pos[(size_t)b * L_ + w] = tid * 8 + i; ++w; }
    if (tid == 255) nsep[b] = cnt[255];
}

// ---------------- K2: out[b,s,:] = mean_{t in seg(b,s)} G[ids[b,t]] + PE[s] -------------------
__global__ void seg_gather(const int* __restrict__ ids, const int* __restrict__ pos,
                           const int* __restrict__ nsep, const __hip_bfloat16* __restrict__ G,
                           float* __restrict__ out, int S) {
    int blk = blockIdx.x;
    int s = blk % S, b = blk / S;
    int tid = threadIdx.x;                             // 256 threads, 3 cols each
    int ns = nsep[b];
    int lo, hi;
    if (s > ns) { lo = 1; hi = 0; }                    // empty segment
    else {
        lo = (s == 0) ? 0 : pos[(size_t)b * L_ + (s - 1)] + 1;
        hi = (s < ns) ? pos[(size_t)b * L_ + s] - 1 : L_ - 1;   // s==ns: tail after last sep
    }
    int cnt = hi - lo + 1; if (cnt < 0) cnt = 0;
    float a0 = 0.f, a1 = 0.f, a2 = 0.f;
    for (int t = lo; t <= hi; ++t) {
        int v = ids[(size_t)b * L_ + t];
        const __hip_bfloat16* gr = G + (size_t)v * H_;
        a0 += __bfloat162float(gr[tid]);
        a1 += __bfloat162float(gr[tid + 256]);
        a2 += __bfloat162float(gr[tid + 512]);
    }
    float inv = (cnt > 0) ? 1.f / (float)cnt : 0.f;
    float* orow = out + ((size_t)b * S + s) * H_;
    const float cexp = -9.210340371976184f / (float)H_;   // -ln(10000)/H
    float acc[3] = {a0, a1, a2};
    #pragma unroll
    for (int c = 0; c < 3; ++c) {
        int n = tid + c * 256;
        int i = n >> 1;
        float div = expf((float)(2 * i) * cexp);
        float ang = (float)s * div;
        float pe  = (n & 1) ? cosf(ang) : sinf(ang);
        orow[n] = acc[c] * inv + pe;
    }
}

// ---------------- host launcher ----------------
extern "C" void kernel_launch(void* const* d_in, const int* in_sizes, int n_in,
                              void* d_out, int out_size, void* d_ws, size_t ws_size,
                              hipStream_t stream) {
    const int*   ids  = (const int*)d_in[0];
    const int*   sep  = (const int*)d_in[1];
    const float* emb  = (const float*)d_in[3];
    const float* g1   = (const float*)d_in[4];
    const float* b1   = (const float*)d_in[5];
    const float* W    = (const float*)d_in[6];
    const float* bias = (const float*)d_in[7];
    const float* g2   = (const float*)d_in[8];
    const float* b2   = (const float*)d_in[9];
    float* out = (float*)d_out;

    int S = out_size / (B_ * H_);                      // 128

    // workspace layout (all 256B-aligned)
    char* ws = (char*)d_ws;
    __hip_bfloat16* Wp  = (__hip_bfloat16*)(ws);                         // 491,520 B
    __hip_bfloat16* h1  = (__hip_bfloat16*)(ws + 491520);                // 19,537,920 B
    __hip_bfloat16* G   = (__hip_bfloat16*)(ws + 491520 + 19537920);     // 46,891,008 B
    int* pos  = (int*)(ws + 491520 + 19537920 + 46891008);               // 262,144 B
    int* nsep = (int*)(ws + 491520 + 19537920 + 46891008 + 262144);      // 128 B
    (void)ws_size; (void)n_in; (void)in_sizes;

    pack_w   <<<(NT * KT * 64 + 255) / 256, 256, 0, stream>>>(W, Wp);
    embed_ln1<<<VPAD / 4, 256, 0, stream>>>(emb, g1, b1, h1);
    gemm_ln2 <<<VPAD / MB, 512, 0, stream>>>(h1, Wp, bias, g2, b2, G);
    sep_scan <<<B_, 256, 0, stream>>>(sep, pos, nsep);
    seg_gather<<<B_ * S, 256, 0, stream>>>(ids, pos, nsep, G, out, S);
}

// Round 10
// 82.918 us; speedup vs baseline: 1.3252x; 1.0406x over previous
//
#include <hip/hip_runtime.h>
#include <hip/hip_bf16.h>

// Shapes (fixed by setup_inputs): B=32, L=2048, V=30522, Dw=300, H=768, S=L/P=128
#define B_   32
#define L_   2048
#define V_   30522
#define DW   300
#define H_   768
#define KP   320              // Dw padded to multiple of 32 for MFMA K
#define NT   (H_/16)          // 48 n-tiles
#define KT   (KP/32)          // 10 k-tiles
#define VPAD 30528            // V rounded up; 30528 = 636 * 48 exactly
#define MB   48               // rows per block (3 m-tiles)
#define NW   6                // n-tiles per wave (8 waves x 6 = 48)
#define APAD 336              // padded LDS row stride (bf16): 672 B rows (16B-aligned);
                              // b128 start-bank spread 16 distinct -> ~4-way max (1.58x, m136)

typedef __attribute__((ext_vector_type(8))) short bf16x8;
typedef __attribute__((ext_vector_type(4))) float f32x4;

// ---------------- K0a: pack W [300][768] fp32 -> Wp bf16, fragment f = kt*NT + n --------------
// Wp[f*64 + lane] = 8 bf16: W[k0+j][col], col = n*16 + (lane&15), k0 = kt*32 + (lane>>4)*8.
__global__ void pack_w(const float* __restrict__ W, __hip_bfloat16* __restrict__ Wp) {
    int t = blockIdx.x * 256 + threadIdx.x;           // [0, NT*KT*64)
    if (t >= NT * KT * 64) return;
    int lane = t & 63;
    int f    = t >> 6;
    int n    = f % NT;
    int kt   = f / NT;
    int col  = n * 16 + (lane & 15);
    int k0   = kt * 32 + (lane >> 4) * 8;
    union { __hip_bfloat16 h[8]; int4 v; } u;
    #pragma unroll
    for (int j = 0; j < 8; ++j) {
        int k = k0 + j;
        float w = (k < DW) ? W[(size_t)k * H_ + col] : 0.f;
        u.h[j] = __float2bfloat16(w);
    }
    reinterpret_cast<int4*>(Wp)[t] = u.v;
}

// ---------------- K0b: h1 table [VPAD][KP] bf16 = LN1(emb_table) (one wave per vocab row) -----
__global__ void embed_ln1(const float* __restrict__ emb, const float* __restrict__ g1,
                          const float* __restrict__ b1, __hip_bfloat16* __restrict__ h1) {
    int wave = (blockIdx.x * blockDim.x + threadIdx.x) >> 6;
    int lane = threadIdx.x & 63;
    if (wave >= VPAD) return;
    __hip_bfloat16* dst = h1 + (size_t)wave * KP;
    if (wave >= V_) {                                  // zero pad rows
        for (int k = lane; k < KP; k += 64) dst[k] = __float2bfloat16(0.f);
        return;
    }
    const float* row = emb + (size_t)wave * DW;
    float x[5]; float s = 0.f, ss = 0.f;
    #pragma unroll
    for (int i = 0; i < 5; ++i) {                      // 5*64 = 320 covers KP exactly
        int k = lane + i * 64;
        float v = (k < DW) ? row[k] : 0.f;
        x[i] = v; s += v; ss += v * v;
    }
    #pragma unroll
    for (int m = 32; m >= 1; m >>= 1) { s += __shfl_xor(s, m); ss += __shfl_xor(ss, m); }
    float mu   = s / (float)DW;
    float var  = ss / (float)DW - mu * mu;
    float rstd = rsqrtf(var + 1e-12f);
    #pragma unroll
    for (int i = 0; i < 5; ++i) {
        int k = lane + i * 64;
        float o = (k < DW) ? (g1[k] * ((x[i] - mu) * rstd) + b1[k]) : 0.f;
        dst[k] = __float2bfloat16(o);
    }
}

// ---------------- K1: G[v] = LN2(relu(h1[v] @ W + b)) — enforced SW pipeline ------------------
// Block = 48 rows, 8 waves (512 thr); wave w owns n-tiles [w*6, w*6+6) for ALL 48 rows.
// Per fully-unrolled kt-step: issue kt+1's 6 B global loads + 3 A ds_reads, then
// sched_barrier(0) — the fence forbids LLVM from sinking the prefetch below the MFMA
// cluster (the r6-r9 failure mode) -> counted vmcnt/lgkmcnt waits, 1 latency per step.
// A staged once in LDS (APAD=336 padding); kt walk rotated by blockIdx%KT (L2 de-hotspot).
// C/D layout (m89-verified): col = lane&15, row = (lane>>4)*4 + reg.
__global__ void __launch_bounds__(512, 2)
gemm_ln2(const __hip_bfloat16* __restrict__ h1, const __hip_bfloat16* __restrict__ Wp,
         const float* __restrict__ bias, const float* __restrict__ g2,
         const float* __restrict__ b2, __hip_bfloat16* __restrict__ G) {
    __shared__ __hip_bfloat16 sA[MB * APAD];           // 32,256 B
    __shared__ float sred[2][8][MB];                   // 3 KB
    int tid  = threadIdx.x;
    int w    = tid >> 6;
    int lane = tid & 63;
    int r = lane & 15, q = lane >> 4;
    size_t row0 = (size_t)blockIdx.x * MB;

    // ---- stage A: 48 rows x 320 bf16 (30,720 B contiguous in h1) -> padded LDS ----
    const int4* gsrc = reinterpret_cast<const int4*>(h1 + row0 * KP);
    #pragma unroll
    for (int i = 0; i < 4; ++i) {
        int t4 = tid + i * 512;                        // int4 index, [0, 1920)
        if (t4 < MB * KP / 8) {
            int row = t4 / 40;                         // 40 int4 per row
            int col = (t4 % 40) * 8;
            *reinterpret_cast<int4*>(&sA[row * APAD + col]) = gsrc[t4];
        }
    }

    f32x4 acc[NW][3];
    #pragma unroll
    for (int nl = 0; nl < NW; ++nl)
        #pragma unroll
        for (int m = 0; m < 3; ++m) acc[nl][m] = (f32x4){0.f, 0.f, 0.f, 0.f};

    const bf16x8* Bv = reinterpret_cast<const bf16x8*>(Wp) + (size_t)w * NW * 64 + lane;
    const char* sAc = reinterpret_cast<const char*>(sA);
    const int abase = r * (APAD * 2) + q * 16;         // lane's A byte base (m=0, kt=0)
    int phase = (int)(blockIdx.x % KT);

    bf16x8 bbuf[2][NW];
    bf16x8 abuf[2][3];

    // prologue: issue B loads for kt=phase (independent of LDS), then barrier for sA
    {
        const bf16x8* bp = Bv + (size_t)phase * NT * 64;
        #pragma unroll
        for (int nl = 0; nl < NW; ++nl) bbuf[0][nl] = bp[nl * 64];
    }
    __syncthreads();                                   // sA ready (also drains prologue B)
    #pragma unroll
    for (int m = 0; m < 3; ++m)
        abuf[0][m] = *reinterpret_cast<const bf16x8*>(
            sAc + abase + m * (16 * APAD * 2) + phase * 64);

    #pragma unroll                                     // FULL unroll: all buf indices static
    for (int i = 0; i < KT; ++i) {
        const int cur = i & 1, nxt = (i + 1) & 1;
        if (i + 1 < KT) {                              // prefetch kt+1 (B global + A LDS)
            int ktn = phase + i + 1; if (ktn >= KT) ktn -= KT;
            const bf16x8* bp = Bv + (size_t)ktn * NT * 64;
            #pragma unroll
            for (int nl = 0; nl < NW; ++nl) bbuf[nxt][nl] = bp[nl * 64];
            #pragma unroll
            for (int m = 0; m < 3; ++m)
                abuf[nxt][m] = *reinterpret_cast<const bf16x8*>(
                    sAc + abase + m * (16 * APAD * 2) + ktn * 64);
        }
        __builtin_amdgcn_sched_barrier(0);             // prefetch may NOT sink below MFMAs
        #pragma unroll
        for (int nl = 0; nl < NW; ++nl) {
            acc[nl][0] = __builtin_amdgcn_mfma_f32_16x16x32_bf16(abuf[cur][0], bbuf[cur][nl], acc[nl][0], 0, 0, 0);
            acc[nl][1] = __builtin_amdgcn_mfma_f32_16x16x32_bf16(abuf[cur][1], bbuf[cur][nl], acc[nl][1], 0, 0, 0);
            acc[nl][2] = __builtin_amdgcn_mfma_f32_16x16x32_bf16(abuf[cur][2], bbuf[cur][nl], acc[nl][2], 0, 0, 0);
        }
    }

    // bias + relu + in-wave partial stats (over this wave's 96 cols)
    float s_[3][4], ss_[3][4];
    #pragma unroll
    for (int m = 0; m < 3; ++m)
        #pragma unroll
        for (int j = 0; j < 4; ++j) { s_[m][j] = 0.f; ss_[m][j] = 0.f; }
    #pragma unroll
    for (int nl = 0; nl < NW; ++nl) {
        float bn = bias[w * 96 + nl * 16 + r];
        #pragma unroll
        for (int m = 0; m < 3; ++m)
            #pragma unroll
            for (int j = 0; j < 4; ++j) {
                float v = acc[nl][m][j] + bn;
                v = v > 0.f ? v : 0.f;
                acc[nl][m][j] = v;
                s_[m][j] += v; ss_[m][j] += v * v;
            }
    }
    #pragma unroll
    for (int msk = 1; msk < 16; msk <<= 1)             // reduce across the 16 r-lanes
        #pragma unroll
        for (int m = 0; m < 3; ++m)
            #pragma unroll
            for (int j = 0; j < 4; ++j) {
                s_[m][j]  += __shfl_xor(s_[m][j],  msk);
                ss_[m][j] += __shfl_xor(ss_[m][j], msk);
            }
    if (r == 0) {                                      // publish wave partials
        #pragma unroll
        for (int m = 0; m < 3; ++m)
            #pragma unroll
            for (int j = 0; j < 4; ++j) {
                int row = m * 16 + q * 4 + j;
                sred[0][w][row] = s_[m][j];
                sred[1][w][row] = ss_[m][j];
            }
    }
    __syncthreads();

    #pragma unroll
    for (int m = 0; m < 3; ++m) {
        #pragma unroll
        for (int j = 0; j < 4; ++j) {
            int row = m * 16 + q * 4 + j;
            float ts = 0.f, tss = 0.f;
            #pragma unroll
            for (int ww = 0; ww < 8; ++ww) { ts += sred[0][ww][row]; tss += sred[1][ww][row]; }
            float mu   = ts / (float)H_;
            float var  = tss / (float)H_ - mu * mu;
            float rstd = rsqrtf(var + 1e-12f);
            s_[m][j]  = mu;                            // reuse as mu
            ss_[m][j] = rstd;                          // reuse as rstd
        }
    }
    #pragma unroll
    for (int nl = 0; nl < NW; ++nl) {
        int col = w * 96 + nl * 16 + r;
        float gg = g2[col], bb = b2[col];
        #pragma unroll
        for (int m = 0; m < 3; ++m)
            #pragma unroll
            for (int j = 0; j < 4; ++j) {
                size_t rowg = row0 + m * 16 + q * 4 + j;
                float val = gg * (acc[nl][m][j] - s_[m][j]) * ss_[m][j] + bb;
                G[rowg * H_ + col] = __float2bfloat16(val);
            }
    }
}

// ---------------- K1.5: per-batch-row separator positions (general mask handling) -------------
__global__ void sep_scan(const int* __restrict__ sep, int* __restrict__ pos, int* __restrict__ nsep) {
    int b = blockIdx.x;
    const int* row = sep + (size_t)b * L_;
    __shared__ int cnt[256];
    int tid = threadIdx.x;
    int local[8]; int c = 0;
    #pragma unroll
    for (int i = 0; i < 8; ++i) { int v = row[tid * 8 + i]; local[i] = v; c += v; }
    cnt[tid] = c; __syncthreads();
    for (int ofs = 1; ofs < 256; ofs <<= 1) {          // Hillis-Steele inclusive scan
        int v = (tid >= ofs) ? cnt[tid - ofs] : 0;
        __syncthreads();
        cnt[tid] += v;
        __syncthreads();
    }
    int w = cnt[tid] - c;                              // exclusive prefix
    #pragma unroll
    for (int i = 0; i < 8; ++i)
        if (local[i]) { pos[(size_t)b * L_ + w] = tid * 8 + i; ++w; }
    if (tid == 255) nsep[b] = cnt[255];
}

// ---------------- K2: out[b,s,:] = mean_{t in seg(b,s)} G[ids[b,t]] + PE[s] -------------------
__global__ void seg_gather(const int* __restrict__ ids, const int* __restrict__ pos,
                           const int* __restrict__ nsep, const __hip_bfloat16* __restrict__ G,
                           float* __restrict__ out, int S) {
    int blk = blockIdx.x;
    int s = blk % S, b = blk / S;
    int tid = threadIdx.x;                             // 256 threads, 3 cols each
    int ns = nsep[b];
    int lo, hi;
    if (s > ns) { lo = 1; hi = 0; }                    // empty segment
    else {
        lo = (s == 0) ? 0 : pos[(size_t)b * L_ + (s - 1)] + 1;
        hi = (s < ns) ? pos[(size_t)b * L_ + s] - 1 : L_ - 1;   // s==ns: tail after last sep
    }
    int cnt = hi - lo + 1; if (cnt < 0) cnt = 0;
    float a0 = 0.f, a1 = 0.f, a2 = 0.f;
    for (int t = lo; t <= hi; ++t) {
        int v = ids[(size_t)b * L_ + t];
        const __hip_bfloat16* gr = G + (size_t)v * H_;
        a0 += __bfloat162float(gr[tid]);
        a1 += __bfloat162float(gr[tid + 256]);
        a2 += __bfloat162float(gr[tid + 512]);
    }
    float inv = (cnt > 0) ? 1.f / (float)cnt : 0.f;
    float* orow = out + ((size_t)b * S + s) * H_;
    const float cexp = -9.210340371976184f / (float)H_;   // -ln(10000)/H
    float acc[3] = {a0, a1, a2};
    #pragma unroll
    for (int c = 0; c < 3; ++c) {
        int n = tid + c * 256;
        int i = n >> 1;
        float div = expf((float)(2 * i) * cexp);
        float ang = (float)s * div;
        float pe  = (n & 1) ? cosf(ang) : sinf(ang);
        orow[n] = acc[c] * inv + pe;
    }
}

// ---------------- host launcher ----------------
extern "C" void kernel_launch(void* const* d_in, const int* in_sizes, int n_in,
                              void* d_out, int out_size, void* d_ws, size_t ws_size,
                              hipStream_t stream) {
    const int*   ids  = (const int*)d_in[0];
    const int*   sep  = (const int*)d_in[1];
    const float* emb  = (const float*)d_in[3];
    const float* g1   = (const float*)d_in[4];
    const float* b1   = (const float*)d_in[5];
    const float* W    = (const float*)d_in[6];
    const float* bias = (const float*)d_in[7];
    const float* g2   = (const float*)d_in[8];
    const float* b2   = (const float*)d_in[9];
    float* out = (float*)d_out;

    int S = out_size / (B_ * H_);                      // 128

    // workspace layout (all 256B-aligned)
    char* ws = (char*)d_ws;
    __hip_bfloat16* Wp  = (__hip_bfloat16*)(ws);                         // 491,520 B
    __hip_bfloat16* h1  = (__hip_bfloat16*)(ws + 491520);                // 19,537,920 B
    __hip_bfloat16* G   = (__hip_bfloat16*)(ws + 491520 + 19537920);     // 46,891,008 B
    int* pos  = (int*)(ws + 491520 + 19537920 + 46891008);               // 262,144 B
    int* nsep = (int*)(ws + 491520 + 19537920 + 46891008 + 262144);      // 128 B
    (void)ws_size; (void)n_in; (void)in_sizes;

    pack_w   <<<(NT * KT * 64 + 255) / 256, 256, 0, stream>>>(W, Wp);
    embed_ln1<<<VPAD / 4, 256, 0, stream>>>(emb, g1, b1, h1);
    gemm_ln2 <<<VPAD / MB, 512, 0, stream>>>(h1, Wp, bias, g2, b2, G);
    sep_scan <<<B_, 256, 0, stream>>>(sep, pos, nsep);
    seg_gather<<<B_ * S, 256, 0, stream>>>(ids, pos, nsep, G, out, S);
}